// Round 3
// baseline (566.126 us; speedup 1.0000x reference)
//
#include <hip/hip_runtime.h>
#include <stdint.h>

#define NROWS 131072
#define DIM 256

typedef __attribute__((ext_vector_type(4))) float f32x4;
typedef __attribute__((ext_vector_type(8))) __bf16 bf16x8;
typedef __attribute__((ext_vector_type(4))) short s16x4;
typedef __attribute__((ext_vector_type(8))) short s16x8;

__device__ __forceinline__ unsigned short f2bf(float f) {
  union { float f; unsigned u; } x; x.f = f;
  unsigned r = x.u + 0x7fffu + ((x.u >> 16) & 1u);
  return (unsigned short)(r >> 16);
}

// ---------------- LN stats + global absmax of xn, for the raw input x ----------------
__global__ __launch_bounds__(256) void k_stats(const float* __restrict__ x,
                                               float* __restrict__ mu_o, float* __restrict__ rs_o,
                                               unsigned* __restrict__ gslot) {
  const int l = threadIdx.x & 63;
  const int gw = blockIdx.x * 4 + (threadIdx.x >> 6);  // 8192 waves
  float gmax = 0.f;
  for (int i = 0; i < 16; ++i) {
    const int row = gw * 16 + i;
    f32x4 v = *(const f32x4*)(x + (size_t)row * DIM + l * 4);
    float s = v.x + v.y + v.z + v.w;
    #pragma unroll
    for (int m = 1; m < 64; m <<= 1) s += __shfl_xor(s, m);
    const float mu = s * (1.f / 256.f);
    float d0 = v.x - mu, d1 = v.y - mu, d2 = v.z - mu, d3 = v.w - mu;
    float sq = d0 * d0 + d1 * d1 + d2 * d2 + d3 * d3;
    float am = fmaxf(fmaxf(fabsf(d0), fabsf(d1)), fmaxf(fabsf(d2), fabsf(d3)));
    #pragma unroll
    for (int m = 1; m < 64; m <<= 1) {
      sq += __shfl_xor(sq, m);
      am = fmaxf(am, __shfl_xor(am, m));
    }
    const float rstd = rsqrtf(sq * (1.f / 256.f) + 1e-5f);
    if (l == 0) { mu_o[row] = mu; rs_o[row] = rstd; }
    gmax = fmaxf(gmax, am * rstd);
  }
  if (l == 0) atomicMax(gslot + (gw & 63), __float_as_uint(gmax));
}

// ---------------- weight alpha/beta (3 blocks, one per W) ----------------
__global__ __launch_bounds__(256) void k_wstats(const float* __restrict__ W0,
                                                const float* __restrict__ W1,
                                                const float* __restrict__ W2,
                                                float* __restrict__ ab) {
  const float* W = blockIdx.x == 0 ? W0 : (blockIdx.x == 1 ? W1 : W2);
  float s = 0.f, sa = 0.f;
  for (int i = threadIdx.x; i < 65536; i += 256) {
    float v = W[i];
    s += v; sa += fabsf(v);
  }
  #pragma unroll
  for (int m = 1; m < 64; m <<= 1) { s += __shfl_xor(s, m); sa += __shfl_xor(sa, m); }
  __shared__ float bs[4], ba[4];
  const int w = threadIdx.x >> 6, l = threadIdx.x & 63;
  if (l == 0) { bs[w] = s; ba[w] = sa; }
  __syncthreads();
  if (threadIdx.x == 0) {
    float S = bs[0] + bs[1] + bs[2] + bs[3];
    float SA = ba[0] + ba[1] + ba[2] + ba[3];
    ab[blockIdx.x] = S * (1.f / 65536.f);
    ab[3 + blockIdx.x] = fmaxf(SA * (1.f / 65536.f), 1e-8f);
  }
}

// ---------------- pack wb = sign(W - alpha) into MFMA B-fragment order ----------------
// packed bf16 index p = ((kt*16 + nt)*64 + lane)*8 + r  ->  B[k][j], k = kt*32 + 8*(lane>>4) + r,
// j = nt*16 + (lane&15), B[k][j] = sign(W[j][k] - alpha)
__global__ __launch_bounds__(256) void k_pack(const float* __restrict__ W0,
                                              const float* __restrict__ W1,
                                              const float* __restrict__ W2,
                                              const float* __restrict__ ab,
                                              unsigned short* __restrict__ bp) {
  const int layer = blockIdx.y;
  const float* W = layer == 0 ? W0 : (layer == 1 ? W1 : W2);
  const float alpha = ab[layer];
  const int p = blockIdx.x * 256 + threadIdx.x;  // 0..65535
  const int r = p & 7, l = (p >> 3) & 63, nt = (p >> 9) & 15, kt = p >> 13;
  const int k = kt * 32 + ((l >> 4) << 3) + r;
  const int j = nt * 16 + (l & 15);
  const float wv = W[j * 256 + k] - alpha;
  bp[layer * 65536 + p] = f2bf(wv > 0.f ? 1.f : -1.f);
}

// ---------------- fused quant + GEMM + scale (+relu + next-layer LN stats) ----------------
// block: 256 thr = 4 waves; tile 64 rows x 256 cols; K=256 in 4 steps of 64
// NOTE: src and bout may ALIAS (layer 3 reads h2 from d_out, writes out in place).
// Safe: each block reads only its own 64 rows (all reads precede its writes).
template <int FINAL>
__global__ __launch_bounds__(256) void k_gemm(
    const float* src, const float* __restrict__ mu, const float* __restrict__ rs,
    const unsigned* __restrict__ gslot, const unsigned short* __restrict__ bp,
    const float* __restrict__ beta_p,
    float* __restrict__ hout, float* bout,
    float* __restrict__ mu_n, float* __restrict__ rs_n, unsigned* __restrict__ gslot_n) {
  __shared__ unsigned short Ab[64][72];   // +8 pad to spread banks
  __shared__ unsigned short Bb[16384];    // 64k x 256n bf16 fragments, 32 KB
  __shared__ float smu[64], srs[64], sg[1];

  const int t = threadIdx.x, l = t & 63, w = t >> 6;
  const int row0 = blockIdx.x * 64;

  if (t < 64) {
    smu[t] = mu[row0 + t];
    srs[t] = rs[row0 + t];
    float g = __uint_as_float(gslot[t]);
    #pragma unroll
    for (int m = 1; m < 64; m <<= 1) g = fmaxf(g, __shfl_xor(g, m));
    if (t == 0) sg[0] = fmaxf(g, 1e-8f);
  }
  __syncthreads();
  const float gamma = sg[0];
  const float qs = 127.f / gamma;
  const float beta = *beta_p;
  const float oscale = beta * gamma * (1.f / 127.f);

  f32x4 acc[16];
  #pragma unroll
  for (int i = 0; i < 16; ++i) acc[i] = (f32x4){0.f, 0.f, 0.f, 0.f};

  const int ar = t >> 2, aq = t & 3;  // A-staging role: row, quarter
  const float amu = smu[ar], ars = srs[ar];

  for (int s = 0; s < 4; ++s) {
    // stage A: quantize 64 rows x 64 k on the fly
    {
      const float* px = src + (size_t)(row0 + ar) * DIM + s * 64 + aq * 16;
      #pragma unroll
      for (int jj = 0; jj < 4; ++jj) {
        f32x4 v = *(const f32x4*)(px + jj * 4);
        s16x4 q;
        #pragma unroll
        for (int e = 0; e < 4; ++e) {
          float xn = (v[e] - amu) * ars;
          float xs = xn * qs;
          xs = fminf(fmaxf(xs, -127.f), 127.f);
          q[e] = (short)f2bf(rintf(xs));
        }
        *(s16x4*)&Ab[ar][aq * 16 + jj * 4] = q;
      }
    }
    // stage B: contiguous 32 KB chunk of packed fragments
    {
      #pragma unroll
      for (int it = 0; it < 8; ++it) {
        const int off = (it * 256 + t) * 8;
        *(s16x8*)&Bb[off] = *(const s16x8*)(bp + s * 16384 + off);
      }
    }
    __syncthreads();
    #pragma unroll
    for (int kt2 = 0; kt2 < 2; ++kt2) {
      bf16x8 a = *(const bf16x8*)&Ab[(w << 4) + (l & 15)][kt2 * 32 + ((l >> 4) << 3)];
      #pragma unroll
      for (int nt = 0; nt < 16; ++nt) {
        bf16x8 b = *(const bf16x8*)&Bb[((kt2 * 16 + nt) * 64 + l) * 8];
        acc[nt] = __builtin_amdgcn_mfma_f32_16x16x32_bf16(a, b, acc[nt], 0, 0, 0);
      }
    }
    __syncthreads();
  }

  // epilogue: C/D layout (m89-verified): col = lane&15, row = (lane>>4)*4 + reg
  const int colb = l & 15;
  const int g = l >> 4;

  if constexpr (FINAL == 1) {
    #pragma unroll
    for (int nt = 0; nt < 16; ++nt) {
      #pragma unroll
      for (int rr = 0; rr < 4; ++rr) {
        const int grow = row0 + (w << 4) + (g << 2) + rr;
        bout[(size_t)grow * DIM + nt * 16 + colb] = acc[nt][rr] * oscale;
      }
    }
  } else {
    float sum[4] = {0.f, 0.f, 0.f, 0.f};
    #pragma unroll
    for (int nt = 0; nt < 16; ++nt) {
      #pragma unroll
      for (int rr = 0; rr < 4; ++rr) {
        float h = fmaxf(acc[nt][rr] * oscale, 0.f);
        acc[nt][rr] = h;
        sum[rr] += h;
        hout[(size_t)(row0 + (w << 4) + (g << 2) + rr) * DIM + nt * 16 + colb] = h;
      }
    }
    float gmax = 0.f;
    #pragma unroll
    for (int rr = 0; rr < 4; ++rr) {
      float s_ = sum[rr];
      s_ += __shfl_xor(s_, 1); s_ += __shfl_xor(s_, 2);
      s_ += __shfl_xor(s_, 4); s_ += __shfl_xor(s_, 8);
      const float m_ = s_ * (1.f / 256.f);
      float sq = 0.f, am = 0.f;
      #pragma unroll
      for (int nt = 0; nt < 16; ++nt) {
        float d = acc[nt][rr] - m_;
        sq += d * d;
        am = fmaxf(am, fabsf(d));
      }
      sq += __shfl_xor(sq, 1); sq += __shfl_xor(sq, 2);
      sq += __shfl_xor(sq, 4); sq += __shfl_xor(sq, 8);
      am = fmaxf(am, __shfl_xor(am, 1)); am = fmaxf(am, __shfl_xor(am, 2));
      am = fmaxf(am, __shfl_xor(am, 4)); am = fmaxf(am, __shfl_xor(am, 8));
      const float rstd = rsqrtf(sq * (1.f / 256.f) + 1e-5f);
      const int grow = row0 + (w << 4) + (g << 2) + rr;
      if (colb == 0) { mu_n[grow] = m_; rs_n[grow] = rstd; }
      gmax = fmaxf(gmax, am * rstd);
    }
    gmax = fmaxf(gmax, __shfl_xor(gmax, 16));
    gmax = fmaxf(gmax, __shfl_xor(gmax, 32));
    if (l == 0) atomicMax(gslot_n + (blockIdx.x & 63), __float_as_uint(gmax));
  }
}

extern "C" void kernel_launch(void* const* d_in, const int* in_sizes, int n_in,
                              void* d_out, int out_size, void* d_ws, size_t ws_size,
                              hipStream_t stream) {
  const float* x  = (const float*)d_in[0];
  const float* W1 = (const float*)d_in[1];
  const float* W2 = (const float*)d_in[2];
  const float* W3 = (const float*)d_in[3];

  char* ws = (char*)d_ws;
  unsigned* gslot = (unsigned*)ws;                      // [3][64] u32
  float* ab = (float*)(ws + 1024);                      // alpha[3], beta[3]
  float* muv = (float*)(ws + 4096);                     // [3][131072] f32
  float* rsv = (float*)(ws + 4096 + 3 * 524288);        // [3][131072] f32
  unsigned short* bp = (unsigned short*)(ws + 3149824); // [3][65536] bf16
  float* h1 = (float*)(ws + 4194304);                   // [131072][256] f32
  float* h2 = (float*)d_out;                            // reuse output buffer for h2

  hipMemsetAsync(gslot, 0, 768, stream);
  k_wstats<<<3, 256, 0, stream>>>(W1, W2, W3, ab);
  dim3 pg(256, 3);
  k_pack<<<pg, 256, 0, stream>>>(W1, W2, W3, ab, bp);
  k_stats<<<2048, 256, 0, stream>>>(x, muv, rsv, gslot);

  k_gemm<0><<<2048, 256, 0, stream>>>(x, muv, rsv, gslot, bp, ab + 3,
                                      h1, nullptr,
                                      muv + 131072, rsv + 131072, gslot + 64);
  k_gemm<0><<<2048, 256, 0, stream>>>(h1, muv + 131072, rsv + 131072, gslot + 64,
                                      bp + 65536, ab + 4,
                                      h2, nullptr,
                                      muv + 262144, rsv + 262144, gslot + 128);
  k_gemm<1><<<2048, 256, 0, stream>>>(h2, muv + 262144, rsv + 262144, gslot + 128,
                                      bp + 131072, ab + 5,
                                      nullptr, (float*)d_out,
                                      nullptr, nullptr, nullptr);
}

// Round 5
// 442.651 us; speedup vs baseline: 1.2789x; 1.2789x over previous
//
#include <hip/hip_runtime.h>
#include <stdint.h>

#define NROWS 131072
#define DIM 256

typedef __attribute__((ext_vector_type(4))) float f32x4;
typedef __attribute__((ext_vector_type(8))) __bf16 bf16x8;
typedef __attribute__((ext_vector_type(4))) short s16x4;
typedef __attribute__((ext_vector_type(8))) short s16x8;

// exact f32 -> bf16 truncation: valid when the value is exactly representable
// in bf16 (integers |v| <= 255, or +-1): low 16 mantissa bits are zero.
__device__ __forceinline__ short bftrunc(float f) {
  return (short)(__float_as_uint(f) >> 16);
}

__device__ __forceinline__ void gload_lds16(const unsigned short* g, unsigned short* lds) {
  __builtin_amdgcn_global_load_lds((const __attribute__((address_space(1))) void*)g,
                                   (__attribute__((address_space(3))) void*)lds, 16, 0, 0);
}

// ---------------- LN stats + global absmax of xn, for the raw input x ----------------
__global__ __launch_bounds__(256) void k_stats(const float* __restrict__ x,
                                               float* __restrict__ mu_o, float* __restrict__ rs_o,
                                               unsigned* __restrict__ gslot) {
  const int l = threadIdx.x & 63;
  const int gw = blockIdx.x * 4 + (threadIdx.x >> 6);  // 8192 waves
  float gmax = 0.f;
  for (int i = 0; i < 16; ++i) {
    const int row = gw * 16 + i;
    f32x4 v = *(const f32x4*)(x + (size_t)row * DIM + l * 4);
    float s = v.x + v.y + v.z + v.w;
    #pragma unroll
    for (int m = 1; m < 64; m <<= 1) s += __shfl_xor(s, m);
    const float mu = s * (1.f / 256.f);
    float d0 = v.x - mu, d1 = v.y - mu, d2 = v.z - mu, d3 = v.w - mu;
    float sq = d0 * d0 + d1 * d1 + d2 * d2 + d3 * d3;
    float am = fmaxf(fmaxf(fabsf(d0), fabsf(d1)), fmaxf(fabsf(d2), fabsf(d3)));
    #pragma unroll
    for (int m = 1; m < 64; m <<= 1) {
      sq += __shfl_xor(sq, m);
      am = fmaxf(am, __shfl_xor(am, m));
    }
    const float rstd = rsqrtf(sq * (1.f / 256.f) + 1e-5f);
    if (l == 0) { mu_o[row] = mu; rs_o[row] = rstd; }
    gmax = fmaxf(gmax, am * rstd);
  }
  if (l == 0) atomicMax(gslot + (gw & 63), __float_as_uint(gmax));
}

// ---------------- weight alpha/beta: stage 1 (64 blocks x 3 layers) ----------------
__global__ __launch_bounds__(256) void k_wstats1(const float* __restrict__ W0,
                                                 const float* __restrict__ W1,
                                                 const float* __restrict__ W2,
                                                 float2* __restrict__ part) {
  const int layer = blockIdx.y;
  const float* W = layer == 0 ? W0 : (layer == 1 ? W1 : W2);
  const int idx = (blockIdx.x * 256 + threadIdx.x) * 4;
  f32x4 v = *(const f32x4*)(W + idx);
  float s = v.x + v.y + v.z + v.w;
  float sa = fabsf(v.x) + fabsf(v.y) + fabsf(v.z) + fabsf(v.w);
  #pragma unroll
  for (int m = 1; m < 64; m <<= 1) { s += __shfl_xor(s, m); sa += __shfl_xor(sa, m); }
  __shared__ float bs[4], ba[4];
  const int w = threadIdx.x >> 6, l = threadIdx.x & 63;
  if (l == 0) { bs[w] = s; ba[w] = sa; }
  __syncthreads();
  if (threadIdx.x == 0) {
    float2 p;
    p.x = bs[0] + bs[1] + bs[2] + bs[3];
    p.y = ba[0] + ba[1] + ba[2] + ba[3];
    part[layer * 64 + blockIdx.x] = p;
  }
}

// ---------------- weight alpha/beta: stage 2 (3 blocks x 64 threads) ----------------
__global__ __launch_bounds__(64) void k_wstats2(const float2* __restrict__ part,
                                                float* __restrict__ ab) {
  const int layer = blockIdx.x;
  float2 p = part[layer * 64 + threadIdx.x];
  float s = p.x, sa = p.y;
  #pragma unroll
  for (int m = 1; m < 64; m <<= 1) { s += __shfl_xor(s, m); sa += __shfl_xor(sa, m); }
  if (threadIdx.x == 0) {
    ab[layer] = s * (1.f / 65536.f);
    ab[3 + layer] = fmaxf(sa * (1.f / 65536.f), 1e-8f);
  }
}

// ---------------- pack wb = sign(W - alpha) into MFMA B-fragment order ----------------
// packed bf16 index p = ((kt*16 + nt)*64 + lane)*8 + r  ->  B[k][j], k = kt*32 + 8*(lane>>4) + r,
// j = nt*16 + (lane&15), B[k][j] = sign(W[j][k] - alpha)
__global__ __launch_bounds__(256) void k_pack(const float* __restrict__ W0,
                                              const float* __restrict__ W1,
                                              const float* __restrict__ W2,
                                              const float* __restrict__ ab,
                                              unsigned short* __restrict__ bp) {
  const int layer = blockIdx.y;
  const float* W = layer == 0 ? W0 : (layer == 1 ? W1 : W2);
  const float alpha = ab[layer];
  const int p = blockIdx.x * 256 + threadIdx.x;  // 0..65535
  const int r = p & 7, l = (p >> 3) & 63, nt = (p >> 9) & 15, kt = p >> 13;
  const int k = kt * 32 + ((l >> 4) << 3) + r;
  const int j = nt * 16 + (l & 15);
  bp[layer * 65536 + p] = (W[j * 256 + k] > alpha) ? 0x3F80u : 0xBF80u;  // +1 / -1 bf16
}

// ---------------- fused quant + GEMM + scale (+relu + next-layer LN stats) ----------------
// block: 256 thr = 4 waves; tile 128 rows x 256 cols; wave = 32 rows x 256 cols (2 m-tiles)
// K=256 in 4 steps of 64. Grid: 1024.
// NOTE: src and bout may ALIAS (layer 3 reads h2 from d_out, writes out in place).
// Safe: each block reads only its own 128 rows (all reads precede its writes).
template <int FINAL>
__global__ __launch_bounds__(256, 2) void k_gemm(
    const float* src, const float* __restrict__ mu, const float* __restrict__ rs,
    const unsigned* __restrict__ gslot, const unsigned short* __restrict__ bp,
    const float* __restrict__ beta_p,
    float* __restrict__ hout, float* bout,
    float* __restrict__ mu_n, float* __restrict__ rs_n, unsigned* __restrict__ gslot_n) {
  __shared__ unsigned short Ab[128][72];  // 18.4 KB, +8 pad
  __shared__ unsigned short Bb[16384];    // 32 KB: 64k x 256n bf16 fragments (linear copy of bp chunk)
  __shared__ float smu[128], srs[128], sg[1];

  const int t = threadIdx.x, l = t & 63, w = t >> 6;
  const int row0 = blockIdx.x * 128;

  if (t < 128) {
    smu[t] = mu[row0 + t];
    srs[t] = rs[row0 + t];
  } else if (t >= 192) {
    float g = __uint_as_float(gslot[t - 192]);
    #pragma unroll
    for (int m = 1; m < 64; m <<= 1) g = fmaxf(g, __shfl_xor(g, m));
    if (t == 192) sg[0] = fmaxf(g, 1e-8f);
  }
  __syncthreads();
  const float gamma = sg[0];
  const float qs = 127.f / gamma;
  const float beta = *beta_p;
  const float oscale = beta * gamma * (1.f / 127.f);

  f32x4 acc[2][16];
  #pragma unroll
  for (int mt = 0; mt < 2; ++mt)
    #pragma unroll
    for (int i = 0; i < 16; ++i) acc[mt][i] = (f32x4){0.f, 0.f, 0.f, 0.f};

  // A-staging role: 2 threads per row, each covers 32 k
  const int ar = t >> 1, ah = t & 1;
  const float c1 = srs[ar] * qs;            // rs * 127/gamma
  const float c0 = -smu[ar] * c1;           // fused offset

  for (int s = 0; s < 4; ++s) {
    // stage B first: async DMA (8 x 1KB chunks per wave), overlaps with A quant below
    {
      const unsigned short* bps = bp + s * 16384 + l * 8;
      #pragma unroll
      for (int it = 0; it < 8; ++it) {
        const int c = (w * 8 + it) * 512;
        gload_lds16(bps + c, &Bb[c]);
      }
    }
    // stage A: quantize 128 rows x 64 k on the fly (32 elems/thread)
    {
      const float* px = src + (size_t)(row0 + ar) * DIM + s * 64 + ah * 32;
      #pragma unroll
      for (int jj = 0; jj < 8; ++jj) {
        f32x4 v = *(const f32x4*)(px + jj * 4);
        s16x4 q;
        #pragma unroll
        for (int e = 0; e < 4; ++e) {
          float xs = __builtin_fmaf(v[e], c1, c0);
          xs = fminf(fmaxf(xs, -127.f), 127.f);
          q[e] = bftrunc(rintf(xs));
        }
        *(s16x4*)&Ab[ar][ah * 32 + jj * 4] = q;
      }
    }
    __syncthreads();
    #pragma unroll
    for (int kt2 = 0; kt2 < 2; ++kt2) {
      bf16x8 aF[2];
      #pragma unroll
      for (int mt = 0; mt < 2; ++mt)
        aF[mt] = *(const bf16x8*)&Ab[(w << 5) + (mt << 4) + (l & 15)][kt2 * 32 + ((l >> 4) << 3)];
      #pragma unroll
      for (int nt = 0; nt < 16; ++nt) {
        bf16x8 b = *(const bf16x8*)&Bb[((kt2 * 16 + nt) * 64 + l) * 8];
        acc[0][nt] = __builtin_amdgcn_mfma_f32_16x16x32_bf16(aF[0], b, acc[0][nt], 0, 0, 0);
        acc[1][nt] = __builtin_amdgcn_mfma_f32_16x16x32_bf16(aF[1], b, acc[1][nt], 0, 0, 0);
      }
    }
    __syncthreads();
  }

  // epilogue: C/D layout (m89-verified): col = lane&15, row-in-tile = (lane>>4)*4 + reg
  const int colb = l & 15;
  const int g = l >> 4;

  if constexpr (FINAL == 1) {
    #pragma unroll
    for (int mt = 0; mt < 2; ++mt)
      #pragma unroll
      for (int nt = 0; nt < 16; ++nt)
        #pragma unroll
        for (int rr = 0; rr < 4; ++rr) {
          const int grow = row0 + (w << 5) + (mt << 4) + (g << 2) + rr;
          bout[(size_t)grow * DIM + nt * 16 + colb] = acc[mt][nt][rr] * oscale;
        }
  } else {
    float gmax = 0.f;
    #pragma unroll
    for (int mt = 0; mt < 2; ++mt) {
      float sum[4] = {0.f, 0.f, 0.f, 0.f};
      #pragma unroll
      for (int nt = 0; nt < 16; ++nt)
        #pragma unroll
        for (int rr = 0; rr < 4; ++rr) {
          float h = fmaxf(acc[mt][nt][rr] * oscale, 0.f);
          acc[mt][nt][rr] = h;
          sum[rr] += h;
          hout[(size_t)(row0 + (w << 5) + (mt << 4) + (g << 2) + rr) * DIM + nt * 16 + colb] = h;
        }
      #pragma unroll
      for (int rr = 0; rr < 4; ++rr) {
        float s_ = sum[rr];
        s_ += __shfl_xor(s_, 1); s_ += __shfl_xor(s_, 2);
        s_ += __shfl_xor(s_, 4); s_ += __shfl_xor(s_, 8);
        const float m_ = s_ * (1.f / 256.f);
        float sq = 0.f, am = 0.f;
        #pragma unroll
        for (int nt = 0; nt < 16; ++nt) {
          float d = acc[mt][nt][rr] - m_;
          sq += d * d;
          am = fmaxf(am, fabsf(d));
        }
        sq += __shfl_xor(sq, 1); sq += __shfl_xor(sq, 2);
        sq += __shfl_xor(sq, 4); sq += __shfl_xor(sq, 8);
        am = fmaxf(am, __shfl_xor(am, 1)); am = fmaxf(am, __shfl_xor(am, 2));
        am = fmaxf(am, __shfl_xor(am, 4)); am = fmaxf(am, __shfl_xor(am, 8));
        const float rstd = rsqrtf(sq * (1.f / 256.f) + 1e-5f);
        const int grow = row0 + (w << 5) + (mt << 4) + (g << 2) + rr;
        if (colb == 0) { mu_n[grow] = m_; rs_n[grow] = rstd; }
        gmax = fmaxf(gmax, am * rstd);
      }
    }
    gmax = fmaxf(gmax, __shfl_xor(gmax, 16));
    gmax = fmaxf(gmax, __shfl_xor(gmax, 32));
    if (l == 0) atomicMax(gslot_n + (blockIdx.x & 63), __float_as_uint(gmax));
  }
}

extern "C" void kernel_launch(void* const* d_in, const int* in_sizes, int n_in,
                              void* d_out, int out_size, void* d_ws, size_t ws_size,
                              hipStream_t stream) {
  const float* x  = (const float*)d_in[0];
  const float* W1 = (const float*)d_in[1];
  const float* W2 = (const float*)d_in[2];
  const float* W3 = (const float*)d_in[3];

  char* ws = (char*)d_ws;
  unsigned* gslot = (unsigned*)ws;                      // [3][64] u32
  float* ab = (float*)(ws + 1024);                      // alpha[3], beta[3]
  float2* part = (float2*)(ws + 2048);                  // [3][64] float2 partials
  float* muv = (float*)(ws + 4096);                     // [3][131072] f32
  float* rsv = (float*)(ws + 4096 + 3 * 524288);        // [3][131072] f32
  unsigned short* bp = (unsigned short*)(ws + 3149824); // [3][65536] bf16
  float* h1 = (float*)(ws + 4194304);                   // [131072][256] f32
  float* h2 = (float*)d_out;                            // reuse output buffer for h2

  hipMemsetAsync(gslot, 0, 768, stream);
  dim3 wg(64, 3);
  k_wstats1<<<wg, 256, 0, stream>>>(W1, W2, W3, part);
  k_wstats2<<<3, 64, 0, stream>>>(part, ab);
  dim3 pg(256, 3);
  k_pack<<<pg, 256, 0, stream>>>(W1, W2, W3, ab, bp);
  k_stats<<<2048, 256, 0, stream>>>(x, muv, rsv, gslot);

  k_gemm<0><<<1024, 256, 0, stream>>>(x, muv, rsv, gslot, bp, ab + 3,
                                      h1, nullptr,
                                      muv + 131072, rsv + 131072, gslot + 64);
  k_gemm<0><<<1024, 256, 0, stream>>>(h1, muv + 131072, rsv + 131072, gslot + 64,
                                      bp + 65536, ab + 4,
                                      h2, nullptr,
                                      muv + 262144, rsv + 262144, gslot + 128);
  k_gemm<1><<<1024, 256, 0, stream>>>(h2, muv + 262144, rsv + 262144, gslot + 128,
                                      bp + 131072, ab + 5,
                                      nullptr, (float*)d_out,
                                      nullptr, nullptr, nullptr);
}